// Round 1
// baseline (106.924 us; speedup 1.0000x reference)
//
#include <hip/hip_runtime.h>

#define EPSF 1e-8f
#define MARGINF 0.5f
#define BN 512
#define DD 768

// ---------------- norms ----------------
__global__ __launch_bounds__(256) void norm_kernel(const float* __restrict__ x,
                                                   float* __restrict__ invn) {
    int i = blockIdx.x;
    int t = threadIdx.x;
    float s = 0.f;
    for (int d = t; d < DD; d += 256) {
        float v = x[i * DD + d];
        s += v * v;
    }
    for (int off = 32; off; off >>= 1) s += __shfl_down(s, off, 64);
    __shared__ float red[4];
    if ((t & 63) == 0) red[t >> 6] = s;
    __syncthreads();
    if (t == 0) {
        float tot = red[0] + red[1] + red[2] + red[3];
        float n = fmaxf(sqrtf(tot), EPSF);
        invn[i] = 1.0f / n;
    }
}

// ---------------- gram / cosine distance ----------------
// dist[i][j] = 1 - dot(x_i, x_j) * invn[i] * invn[j]
#define BT 64
#define BK 16
__global__ __launch_bounds__(256) void gram_kernel(const float* __restrict__ x,
                                                   const float* __restrict__ invn,
                                                   float* __restrict__ dist) {
    __shared__ float As[BK][BT + 1];
    __shared__ float Bs[BK][BT + 1];
    int i0 = blockIdx.y * BT;
    int j0 = blockIdx.x * BT;
    int tid = threadIdx.x;
    int lm = tid >> 2;          // 0..63 : row within tile
    int lk = (tid & 3) * 4;     // 0,4,8,12 : k offset (float4)
    int tx = tid & 15, ty = tid >> 4;
    float acc[4][4] = {};
    for (int k0 = 0; k0 < DD; k0 += BK) {
        float4 a = *(const float4*)&x[(i0 + lm) * DD + k0 + lk];
        float4 b = *(const float4*)&x[(j0 + lm) * DD + k0 + lk];
        __syncthreads();  // previous iteration done reading LDS
        As[lk + 0][lm] = a.x; As[lk + 1][lm] = a.y; As[lk + 2][lm] = a.z; As[lk + 3][lm] = a.w;
        Bs[lk + 0][lm] = b.x; Bs[lk + 1][lm] = b.y; Bs[lk + 2][lm] = b.z; Bs[lk + 3][lm] = b.w;
        __syncthreads();
#pragma unroll
        for (int k = 0; k < BK; ++k) {
            float av[4], bv[4];
#pragma unroll
            for (int r = 0; r < 4; ++r) av[r] = As[k][ty * 4 + r];
#pragma unroll
            for (int c = 0; c < 4; ++c) bv[c] = Bs[k][tx * 4 + c];
#pragma unroll
            for (int r = 0; r < 4; ++r)
#pragma unroll
                for (int c = 0; c < 4; ++c) acc[r][c] += av[r] * bv[c];
        }
    }
    float ii[4], jj[4];
#pragma unroll
    for (int r = 0; r < 4; ++r) ii[r] = invn[i0 + ty * 4 + r];
#pragma unroll
    for (int c = 0; c < 4; ++c) jj[c] = invn[j0 + tx * 4 + c];
#pragma unroll
    for (int r = 0; r < 4; ++r)
#pragma unroll
        for (int c = 0; c < 4; ++c)
            dist[(i0 + ty * 4 + r) * BN + j0 + tx * 4 + c] =
                1.0f - acc[r][c] * ii[r] * jj[c];
}

// ---------------- accumulator init ----------------
__global__ void init_kernel(double* acc) {
    acc[0] = 0.0;
    acc[1] = 0.0;
}

// ---------------- triplet accumulation ----------------
// one block per anchor i; thread t owns k = t and k = t+256
__global__ __launch_bounds__(256) void triplet_kernel(const float* __restrict__ dist,
                                                      const int* __restrict__ labels,
                                                      double* __restrict__ acc) {
    int i = blockIdx.x;
    int t = threadIdx.x;
    __shared__ float drow[BN];
    __shared__ int lab[BN];
    drow[t] = dist[i * BN + t];
    drow[t + 256] = dist[i * BN + t + 256];
    lab[t] = labels[t];
    lab[t + 256] = labels[t + 256];
    __syncthreads();
    int li = lab[i];
    float dik0 = drow[t];
    float dik1 = drow[t + 256];
    bool k0ok = (lab[t] != li);
    bool k1ok = (lab[t + 256] != li);
    float sum = 0.f;
    unsigned int cnt = 0;
    for (int j = 0; j < BN; ++j) {
        if (j == i || lab[j] != li) continue;   // wave-uniform branch
        float base = drow[j] + MARGINF;
        float v0 = base - dik0;
        float v1 = base - dik1;
        if (k0ok) {
            if (v0 > 0.f) sum += v0;
            if (v0 > EPSF) cnt++;
        }
        if (k1ok) {
            if (v1 > 0.f) sum += v1;
            if (v1 > EPSF) cnt++;
        }
    }
    for (int off = 32; off; off >>= 1) {
        sum += __shfl_down(sum, off, 64);
        cnt += __shfl_down(cnt, off, 64);
    }
    __shared__ float swred[4];
    __shared__ unsigned int cwred[4];
    if ((t & 63) == 0) { swred[t >> 6] = sum; cwred[t >> 6] = cnt; }
    __syncthreads();
    if (t == 0) {
        float stot = swred[0] + swred[1] + swred[2] + swred[3];
        unsigned int ctot = cwred[0] + cwred[1] + cwred[2] + cwred[3];
        atomicAdd(&acc[0], (double)stot);
        atomicAdd(&acc[1], (double)ctot);
    }
}

// ---------------- finalize ----------------
__global__ void finalize_kernel(const double* __restrict__ acc, float* __restrict__ out) {
    out[0] = (float)(acc[0] / (acc[1] + 1e-8));
}

extern "C" void kernel_launch(void* const* d_in, const int* in_sizes, int n_in,
                              void* d_out, int out_size, void* d_ws, size_t ws_size,
                              hipStream_t stream) {
    const float* x = (const float*)d_in[0];
    const int* labels = (const int*)d_in[1];
    float* out = (float*)d_out;

    char* ws = (char*)d_ws;
    double* acc = (double*)ws;                    // 16 B
    float* invn = (float*)(ws + 256);             // 2 KB
    float* dist = (float*)(ws + 4096);            // 1 MB

    norm_kernel<<<BN, 256, 0, stream>>>(x, invn);
    gram_kernel<<<dim3(BN / BT, BN / BT), 256, 0, stream>>>(x, invn, dist);
    init_kernel<<<1, 1, 0, stream>>>(acc);
    triplet_kernel<<<BN, 256, 0, stream>>>(dist, labels, acc);
    finalize_kernel<<<1, 1, 0, stream>>>(acc, out);
}

// Round 2
// 47.791 us; speedup vs baseline: 2.2373x; 2.2373x over previous
//
#include <hip/hip_runtime.h>

#define EPSF 1e-8f
#define MARGINF 0.5f
#define BN 512
#define DD 768
#define BT 64
#define BK 16
#define PAD 68   // transpose-write banks: 4*68 % 32 == 16 -> max 2-way (free)

// ---------------- norms (+ accumulator zeroing) ----------------
__global__ __launch_bounds__(256) void norm_kernel(const float* __restrict__ x,
                                                   float* __restrict__ invn,
                                                   double* __restrict__ acc) {
    int i = blockIdx.x;
    int t = threadIdx.x;
    if (i == 0 && t == 0) { acc[0] = 0.0; acc[1] = 0.0; }
    float4 v = make_float4(0.f, 0.f, 0.f, 0.f);
    if (t < DD / 4) v = *(const float4*)&x[i * DD + t * 4];
    float s = v.x * v.x + v.y * v.y + v.z * v.z + v.w * v.w;
    for (int off = 32; off; off >>= 1) s += __shfl_down(s, off, 64);
    __shared__ float red[4];
    if ((t & 63) == 0) red[t >> 6] = s;
    __syncthreads();
    if (t == 0) {
        float tot = red[0] + red[1] + red[2] + red[3];
        invn[i] = 1.0f / fmaxf(sqrtf(tot), EPSF);
    }
}

// ---------------- gram partial: dotp[z][i][j] = sum_{k in chunk z} x_i.x_j ----------------
__global__ __launch_bounds__(256) void gram_kernel(const float* __restrict__ x,
                                                   float* __restrict__ dotp,
                                                   int kc) {
    __shared__ float As[BK][PAD];
    __shared__ float Bs[BK][PAD];
    int i0 = blockIdx.y * BT;
    int j0 = blockIdx.x * BT;
    int kbase = blockIdx.z * kc;
    int tid = threadIdx.x;
    int lm = tid >> 2;          // 0..63 row within tile
    int lk = (tid & 3) * 4;     // 0,4,8,12 k offset (float4)
    int tx = tid & 15, ty = tid >> 4;
    float acc[4][4] = {};
    for (int k0 = kbase; k0 < kbase + kc; k0 += BK) {
        float4 a = *(const float4*)&x[(i0 + lm) * DD + k0 + lk];
        float4 b = *(const float4*)&x[(j0 + lm) * DD + k0 + lk];
        __syncthreads();  // previous iteration done reading LDS
        As[lk + 0][lm] = a.x; As[lk + 1][lm] = a.y; As[lk + 2][lm] = a.z; As[lk + 3][lm] = a.w;
        Bs[lk + 0][lm] = b.x; Bs[lk + 1][lm] = b.y; Bs[lk + 2][lm] = b.z; Bs[lk + 3][lm] = b.w;
        __syncthreads();
#pragma unroll
        for (int k = 0; k < BK; ++k) {
            float4 av = *(const float4*)&As[k][ty * 4];
            float4 bv = *(const float4*)&Bs[k][tx * 4];
            float avr[4] = {av.x, av.y, av.z, av.w};
            float bvr[4] = {bv.x, bv.y, bv.z, bv.w};
#pragma unroll
            for (int r = 0; r < 4; ++r)
#pragma unroll
                for (int c = 0; c < 4; ++c) acc[r][c] += avr[r] * bvr[c];
        }
    }
    float* out = dotp + (size_t)blockIdx.z * BN * BN;
#pragma unroll
    for (int r = 0; r < 4; ++r)
        *(float4*)&out[(i0 + ty * 4 + r) * BN + j0 + tx * 4] =
            make_float4(acc[r][0], acc[r][1], acc[r][2], acc[r][3]);
}

// ---------------- triplet accumulation (fused cosine epilogue) ----------------
// one block per anchor i; thread t owns k = t and k = t+256; j-loop walks a
// ballot-built bitmask of positives (lab[j]==lab[i], j!=i) -> ~73 iters not 512.
__global__ __launch_bounds__(256) void triplet_kernel(const float* __restrict__ dotp,
                                                      const float* __restrict__ invn,
                                                      const int* __restrict__ labels,
                                                      double* __restrict__ acc,
                                                      int splitk) {
    int i = blockIdx.x;
    int t = threadIdx.x;
    __shared__ float drow[BN];
    __shared__ int lab[BN];
    __shared__ unsigned long long pmask[8];
    lab[t] = labels[t];
    lab[t + 256] = labels[t + 256];
    float inv_i = invn[i];
#pragma unroll
    for (int e0 = 0; e0 < BN; e0 += 256) {
        int e = e0 + t;
        float s = 0.f;
        for (int z = 0; z < splitk; ++z) s += dotp[(size_t)z * BN * BN + i * BN + e];
        drow[e] = 1.0f - s * inv_i * invn[e];
    }
    __syncthreads();
    int li = lab[i];
    if (t < 64) {
        for (int w = 0; w < 8; ++w) {
            int j = (w << 6) | t;
            unsigned long long m = __ballot(lab[j] == li && j != i);
            if (t == 0) pmask[w] = m;
        }
    }
    __syncthreads();
    float dik0 = drow[t];
    float dik1 = drow[t + 256];
    bool k0ok = (lab[t] != li);
    bool k1ok = (lab[t + 256] != li);
    float sum = 0.f;
    unsigned int cnt = 0;
    for (int w = 0; w < 8; ++w) {
        unsigned long long m = pmask[w];
        while (m) {
            int j = (w << 6) + __ffsll(m) - 1;
            m &= m - 1;
            float base = drow[j] + MARGINF;
            float v0 = base - dik0;
            float v1 = base - dik1;
            if (k0ok) {
                if (v0 > 0.f) sum += v0;
                if (v0 > EPSF) cnt++;
            }
            if (k1ok) {
                if (v1 > 0.f) sum += v1;
                if (v1 > EPSF) cnt++;
            }
        }
    }
    for (int off = 32; off; off >>= 1) {
        sum += __shfl_down(sum, off, 64);
        cnt += __shfl_down(cnt, off, 64);
    }
    __shared__ float swred[4];
    __shared__ unsigned int cwred[4];
    if ((t & 63) == 0) { swred[t >> 6] = sum; cwred[t >> 6] = cnt; }
    __syncthreads();
    if (t == 0) {
        float stot = swred[0] + swred[1] + swred[2] + swred[3];
        unsigned int ctot = cwred[0] + cwred[1] + cwred[2] + cwred[3];
        atomicAdd(&acc[0], (double)stot);
        atomicAdd(&acc[1], (double)ctot);
    }
}

// ---------------- finalize ----------------
__global__ void finalize_kernel(const double* __restrict__ acc, float* __restrict__ out) {
    out[0] = (float)(acc[0] / (acc[1] + 1e-8));
}

extern "C" void kernel_launch(void* const* d_in, const int* in_sizes, int n_in,
                              void* d_out, int out_size, void* d_ws, size_t ws_size,
                              hipStream_t stream) {
    const float* x = (const float*)d_in[0];
    const int* labels = (const int*)d_in[1];
    float* out = (float*)d_out;

    char* ws = (char*)d_ws;
    double* acc = (double*)ws;                    // 16 B
    float* invn = (float*)(ws + 256);             // 2 KB
    float* dotp = (float*)(ws + 4096);            // splitk * 1 MB

    // pick largest split-K (parallelism for gram) that fits the workspace
    size_t avail = ws_size > 4096 ? ws_size - 4096 : 0;
    int splitk = 8;
    while (splitk > 1 && (size_t)splitk * BN * BN * 4 > avail) splitk >>= 1;
    int kc = DD / splitk;  // 96 / 192 / 384 / 768, all multiples of BK

    norm_kernel<<<BN, 256, 0, stream>>>(x, invn, acc);
    gram_kernel<<<dim3(BN / BT, BN / BT, splitk), 256, 0, stream>>>(x, dotp, kc);
    triplet_kernel<<<BN, 256, 0, stream>>>(dotp, invn, labels, acc, splitk);
    finalize_kernel<<<1, 1, 0, stream>>>(acc, out);
}